// Round 1
// baseline (168.007 us; speedup 1.0000x reference)
//
#include <hip/hip_runtime.h>
#include <math.h>

// Problem constants (fixed by setup_inputs): B=4096, T=512, Q=4
#define T_DIM 512
#define T_SHIFT 9
#define GAMMA_F 0.997f
#define EPS_F 1e-3f
// log2(0.997)
#define LOG2_GAMMA (-0.0043345903f)

__device__ __forceinline__ float inv_rescale_f(float x) {
    // sign(x) * (((sqrt(1 + 4*eps*(|x|+1+eps)) - 1) / (2*eps))^2 - 1), sign(0)=0
    float s = (x > 0.f) ? 1.f : ((x < 0.f) ? -1.f : 0.f);
    float sqrt_arg = 1.f + 4.f * EPS_F * (fabsf(x) + 1.f + EPS_F);
    float q = (sqrtf(sqrt_arg) - 1.f) * (1.f / (2.f * EPS_F));
    return s * (q * q - 1.f);
}

__device__ __forceinline__ float rescale_f(float x) {
    // sign(x)*(sqrt(|x|+1)-1) + eps*x   (first term is 0 at x=0, copysign safe)
    return copysignf(sqrtf(fabsf(x) + 1.f) - 1.f, x) + EPS_F * x;
}

__global__ __launch_bounds__(256) void nstep_qloss_kernel(
    const float* __restrict__ cur_q,    // (B,T,4)
    const float* __restrict__ next_q,   // (B,T,4)
    const float* __restrict__ log_p,    // (B,T)
    const float* __restrict__ reward,   // (B,T,4)
    const float* __restrict__ is_done,  // (B,T)
    const float* __restrict__ mask,     // (B,T)
    float* __restrict__ out,            // (B,T,4)
    int BT)
{
    int idx = blockIdx.x * 256 + threadIdx.x;
    if (idx >= BT) return;
    int t = idx & (T_DIM - 1);
    int base = idx - t;                // b*T

    // gamma^j, j=0..4 (compile-time folded)
    const float g1 = GAMMA_F;
    const float g2 = g1 * g1;
    const float g3 = g2 * g1;
    const float g4 = g2 * g2;
    const float gpow[5] = {1.f, g1, g2, g3, g4};

    const float4* reward4 = (const float4*)reward;
    const float4* curq4   = (const float4*)cur_q;
    const float4* nextq4  = (const float4*)next_q;
    float4* out4          = (float4*)out;

    float rs0 = 0.f, rs1 = 0.f, rs2 = 0.f, rs3 = 0.f;  // reward_sum per q
    float Lsum = 0.f;   // sum_j gamma^(j+1) * m*(1-d)*log_p   (q-independent)
    float m_t = 0.f;    // mask at t (j==0)

#pragma unroll
    for (int j = 0; j < 5; ++j) {
        int s = t + j;
        if (s < T_DIM) {
            int o = base + s;
            float mm = mask[o];
            float dd = is_done[o];
            float lp = log_p[o];
            float4 r = reward4[o];
            if (j == 0) m_t = mm;
            float w = gpow[j] * mm;
            rs0 += w * r.x;
            rs1 += w * r.y;
            rs2 += w * r.z;
            rs3 += w * r.w;
            Lsum += (gpow[j] * GAMMA_F) * (mm * (1.f - dd) * lp);
        }
    }

    // next_term: i = min(T-1, t+4); coeff = gamma^i (absolute index, faithful)
    int i = t + 4; if (i > T_DIM - 1) i = T_DIM - 1;
    int oi = base + i;
    float mi = mask[oi];
    float di = is_done[oi];
    float coeff = exp2f((float)i * LOG2_GAMMA);
    float g = coeff * mi * (1.f - di);
    float4 nq = nextq4[oi];
    float nt0 = g * inv_rescale_f(nq.x);
    float nt1 = g * inv_rescale_f(nq.y);
    float nt2 = g * inv_rescale_f(nq.z);
    float nt3 = g * inv_rescale_f(nq.w);

    // log_p_sum per q = inv_num_q * inv_qw[q] * Lsum ; inv_num_q = 1/3
    const float inv_num_q = 1.f / 3.f;
    float Ls = inv_num_q * Lsum;
    // inv_qw = {1, 2, 0, 0.5}; q_w = {1, 0.5, 0, 2}
    float tgt0 = rescale_f(rs0 + nt0 + 1.0f * Ls);
    float tgt1 = rescale_f(rs1 + nt1 + 2.0f * Ls);
    float tgt2 = rescale_f(rs2 + nt2 + 0.0f * Ls);
    float tgt3 = rescale_f(rs3 + nt3 + 0.5f * Ls);

    float4 cq = curq4[idx];
    float4 o;
    float hm = 0.5f * m_t;
    float d0 = cq.x - tgt0;
    float d1 = cq.y - tgt1;
    float d2 = cq.z - tgt2;  (void)d2;
    float d3 = cq.w - tgt3;
    o.x = hm * 1.0f * d0 * d0;
    o.y = hm * 0.5f * d1 * d1;
    o.z = 0.f;               // q_w[2] == 0
    o.w = hm * 2.0f * d3 * d3;
    out4[idx] = o;
}

extern "C" void kernel_launch(void* const* d_in, const int* in_sizes, int n_in,
                              void* d_out, int out_size, void* d_ws, size_t ws_size,
                              hipStream_t stream) {
    const float* cur_q   = (const float*)d_in[0];
    const float* next_q  = (const float*)d_in[1];
    const float* log_p   = (const float*)d_in[2];
    const float* reward  = (const float*)d_in[3];
    const float* is_done = (const float*)d_in[4];
    const float* mask    = (const float*)d_in[5];
    float* out = (float*)d_out;

    int BT = in_sizes[2];               // B*T (log_p flat size)
    int blocks = (BT + 255) / 256;
    hipLaunchKernelGGL(nstep_qloss_kernel, dim3(blocks), dim3(256), 0, stream,
                       cur_q, next_q, log_p, reward, is_done, mask, out, BT);
}